// Round 5
// baseline (382.126 us; speedup 1.0000x reference)
//
#include <hip/hip_runtime.h>
#include <stdint.h>

// D = 128 fixed by the problem.
#define FD 128

typedef __bf16 bf16x8 __attribute__((ext_vector_type(8)));
typedef unsigned short u16x8 __attribute__((ext_vector_type(8)));
typedef float  f32x16 __attribute__((ext_vector_type(16)));

__device__ __forceinline__ unsigned short f2bf(float f) {
    unsigned u = __float_as_uint(f);
    unsigned r = u + 0x7fffu + ((u >> 16) & 1u);   // RNE
    return (unsigned short)(r >> 16);
}
__device__ __forceinline__ float bflo(unsigned u) { return __uint_as_float(u << 16); }
__device__ __forceinline__ float bfhi(unsigned u) { return __uint_as_float(u & 0xffff0000u); }

// ---------------------------------------------------------------------------
// FEATURE PERMUTATION (R5): A/B/S node-rows store features in MFMA-native
// order so the gemm epilogue can emit full-line stores:
//   uint position p = 2*j + t  (j = 0..31, t = 0..1) holds the bf16 pair
//   (feature j + 64*t [lo16], feature j + 64*t + 32 [hi16]).
// aggregate is featurewise, so only its final out-RMW needs the inverse map:
//   f_lo = (lane>>1) + 64*(lane&1), f_hi = f_lo + 32.
// ---------------------------------------------------------------------------

// ---------------------------------------------------------------------------
// prep: weights -> Wf, bf16 in MFMA B-fragment order:
//   Wf[((ct*8 + kt)*64 + lane)*8 + j] = W'[k = kt*16 + (lane>>5)*8 + j]
//                                         [c = ct*32 + (lane&31)]
// where W' = [Wg1 | Wg2 | Ws | Wr] (128 x 512). 512*128 elements = 128 KB.
// Quarter w (ct = 4w..4w+3) is contiguous: Wf[w*16384 .. (w+1)*16384).
// ---------------------------------------------------------------------------
__global__ __launch_bounds__(256) void prep_kernel(
    const float* __restrict__ Wg,
    const float* __restrict__ Ws,
    const float* __restrict__ Wr,
    unsigned short* __restrict__ Wf)
{
    int wid = blockIdx.x * 256 + threadIdx.x;      // 0 .. 65535
    if (wid >= 512 * 128) return;
    int j  = wid & 7;
    int l  = (wid >> 3) & 63;
    int kt = (wid >> 9) & 7;
    int ct = wid >> 12;                        // 0..15
    int k  = kt * 16 + (l >> 5) * 8 + j;       // 0..127
    int c  = ct * 32 + (l & 31);               // 0..511
    float v;
    if (c < 128)      v = Wg[k * FD + c];                    // Wg1
    else if (c < 256) v = Wg[(128 + k) * FD + (c - 128)];    // Wg2
    else if (c < 384) v = Ws[k * FD + (c - 256)];            // Ws
    else              v = Wr[k * FD + (c - 384)];            // Wr
    Wf[wid] = f2bf(v);
}

// ---------------------------------------------------------------------------
// gemm: [A|B|S|R] = h @ [Wg1|Wg2|Ws|Wr]  (N x 512 output, K = 128)
// A(+bg), B, S(+bs) in permuted bf16 layout; R -> out(+br, fp32 canonical).
//
// R4 structure (LDS-stationary weights, grid (256,4), no hot-loop barriers)
// + R5 epilogue: pack the lane's 4 accumulator values for one row into ONE
// uint2 store (256-B fully-covered segments, 16 stores/tile vs 64 2-B
// scatters). R4 counters showed WRITE_SIZE 180 MB vs 128 ideal at 2.2 TB/s
// -- partial-line (64 B) stores were the gemm bottleneck.
// ---------------------------------------------------------------------------
__global__ __launch_bounds__(256, 4) void gemm_kernel(
    const float* __restrict__ h,
    const unsigned short* __restrict__ Wf,
    const float* __restrict__ bg,
    const float* __restrict__ bs,
    const float* __restrict__ br,
    unsigned short* __restrict__ A,
    unsigned short* __restrict__ B,
    unsigned short* __restrict__ S,
    float* __restrict__ out,
    int N)
{
    __shared__ unsigned short Bsh[16384];       // 32 KB: one weight quarter

    const int w    = blockIdx.y;                // 0..3: which weight matrix
    const int lane = threadIdx.x & 63;
    const int wid  = threadIdx.x >> 6;          // wave 0..3

    // ---- stage quarter w into LDS once: 8 passes x (256 threads x 16 B) ----
    {
        const unsigned short* src = Wf + (size_t)w * 16384 + (size_t)threadIdx.x * 8;
        unsigned short* dst = Bsh + (size_t)threadIdx.x * 8;
        #pragma unroll
        for (int p = 0; p < 8; ++p) {
            __builtin_amdgcn_global_load_lds(
                (const __attribute__((address_space(1))) void*)(src + p * 2048),
                (__attribute__((address_space(3))) void*)(dst + p * 2048),
                16, 0, 0);
        }
    }

    // per-wave constants
    const int col_l  = lane & 31;
    const int rhalf  = (lane >> 5) * 4;
    float bias[4];
    #pragma unroll
    for (int i = 0; i < 4; ++i) {
        int col = i * 32 + col_l;
        bias[i] = (w == 0) ? bg[col] : (w == 2) ? bs[col] : (w == 3) ? br[col] : 0.0f;
    }
    unsigned short* dstABS = (w == 0) ? A : (w == 1) ? B : S;

    __syncthreads();   // stage complete; no further barriers

    const int stride = gridDim.x * 128;         // rows per grid sweep (256*128)
    for (int rb0 = blockIdx.x * 128; rb0 < N; rb0 += stride) {
        const int rb = rb0 + wid * 32;
        int arow = rb + (lane & 31);
        if (arow >= N) arow = N - 1;      // clamp tail loads (dup work, guarded store)
        const float* aptr = h + (size_t)arow * FD + (lane >> 5) * 8;

        // A strip: 16 dwordx4, convert to 8 bf16x8 fragments
        bf16x8 afrag[8];
        #pragma unroll
        for (int kt = 0; kt < 8; ++kt) {
            float4 f0 = *(const float4*)(aptr + kt * 16);
            float4 f1 = *(const float4*)(aptr + kt * 16 + 4);
            union { u16x8 u; bf16x8 b; } cv;
            cv.u[0] = f2bf(f0.x); cv.u[1] = f2bf(f0.y);
            cv.u[2] = f2bf(f0.z); cv.u[3] = f2bf(f0.w);
            cv.u[4] = f2bf(f1.x); cv.u[5] = f2bf(f1.y);
            cv.u[6] = f2bf(f1.z); cv.u[7] = f2bf(f1.w);
            afrag[kt] = cv.b;
        }

        f32x16 acc[4];
        #pragma unroll
        for (int i = 0; i < 4; ++i)
            #pragma unroll
            for (int r = 0; r < 16; ++r) acc[i][r] = 0.0f;

        #pragma unroll
        for (int kt = 0; kt < 8; ++kt) {
            #pragma unroll
            for (int i = 0; i < 4; ++i) {
                bf16x8 bfr = *(const bf16x8*)(Bsh + (size_t)((i * 8 + kt) * 64 + lane) * 8);
                acc[i] = __builtin_amdgcn_mfma_f32_32x32x16_bf16(
                             afrag[kt], bfr, acc[i], 0, 0, 0);
            }
        }

        // C/D layout: col = lane&31, row = (reg&3) + 8*(reg>>2) + 4*(lane>>5)
        const bool interior = (rb + 32 <= N);
        if (w == 3) {
            // fp32 out, canonical cols: 128-B segments per store already.
            #pragma unroll
            for (int i = 0; i < 4; ++i) {
                int col = i * 32 + col_l;
                #pragma unroll
                for (int r = 0; r < 16; ++r) {
                    int row = rb + (r & 3) + 8 * (r >> 2) + rhalf;
                    if (interior || row < N)
                        out[(size_t)row * FD + col] = acc[i][r] + bias[i];
                }
            }
        } else {
            // permuted bf16 layout: one uint2 (8 B) per row per lane.
            #pragma unroll
            for (int r = 0; r < 16; ++r) {
                int row = rb + (r & 3) + 8 * (r >> 2) + rhalf;
                if (interior || row < N) {
                    uint2 pk;
                    pk.x = (unsigned)f2bf(acc[0][r] + bias[0])
                         | ((unsigned)f2bf(acc[1][r] + bias[1]) << 16);
                    pk.y = (unsigned)f2bf(acc[2][r] + bias[2])
                         | ((unsigned)f2bf(acc[3][r] + bias[3]) << 16);
                    *(uint2*)(dstABS + (size_t)row * FD + col_l * 4) = pk;
                }
            }
        }
    }
}

// ---------------------------------------------------------------------------
// CSR build: histogram of receivers -> exclusive scan -> scatter send ids.
// idx is int32 [2][E] (harness converts int64 -> int32).
// ---------------------------------------------------------------------------
__global__ __launch_bounds__(256) void hist_kernel(
    const int* __restrict__ idx, int* __restrict__ deg, int E)
{
    int e = blockIdx.x * 256 + threadIdx.x;
    if (e >= E) return;
    atomicAdd(&deg[idx[E + e]], 1);
}

// scan pass 1: per-block sums of deg (1024 elems / block of 256 threads)
__global__ __launch_bounds__(256) void scan1_kernel(
    const int* __restrict__ deg, int* __restrict__ partial, int N)
{
    __shared__ int sh[256];
    int base = blockIdx.x * 1024 + threadIdx.x * 4;
    int s = 0;
    #pragma unroll
    for (int j = 0; j < 4; ++j) s += (base + j < N) ? deg[base + j] : 0;
    sh[threadIdx.x] = s;
    __syncthreads();
    for (int ofs = 128; ofs > 0; ofs >>= 1) {
        if (threadIdx.x < ofs) sh[threadIdx.x] += sh[threadIdx.x + ofs];
        __syncthreads();
    }
    if (threadIdx.x == 0) partial[blockIdx.x] = sh[0];
}

// scan pass 2: single block, exclusive scan of <=256 partials in place
__global__ __launch_bounds__(256) void scan2_kernel(int* __restrict__ partial, int nb)
{
    __shared__ int sh[256];
    int t = threadIdx.x;
    int p = (t < nb) ? partial[t] : 0;
    sh[t] = p;
    __syncthreads();
    for (int ofs = 1; ofs < 256; ofs <<= 1) {
        int x = (t >= ofs) ? sh[t - ofs] : 0;
        __syncthreads();
        sh[t] += x;
        __syncthreads();
    }
    if (t < nb) partial[t] = sh[t] - p;   // exclusive
}

// scan pass 3: recompute local exclusive scan + block offset; IN-PLACE deg->off
__global__ __launch_bounds__(256) void scan3_kernel(
    int* __restrict__ deg, const int* __restrict__ partial, int N)
{
    __shared__ int sh[256];
    int base = blockIdx.x * 1024 + threadIdx.x * 4;
    int v[4];
    #pragma unroll
    for (int j = 0; j < 4; ++j) v[j] = (base + j < N) ? deg[base + j] : 0;
    int tsum = v[0] + v[1] + v[2] + v[3];
    sh[threadIdx.x] = tsum;
    __syncthreads();
    for (int ofs = 1; ofs < 256; ofs <<= 1) {
        int x = (threadIdx.x >= ofs) ? sh[threadIdx.x - ofs] : 0;
        __syncthreads();
        sh[threadIdx.x] += x;
        __syncthreads();
    }
    int run = partial[blockIdx.x] + sh[threadIdx.x] - tsum;  // exclusive at base
    #pragma unroll
    for (int j = 0; j < 4; ++j) {
        if (base + j < N) deg[base + j] = run;
        run += v[j];
    }
}

// scatter: csr[pos] = send, consuming off (after: off[r] = end of segment r;
// start of segment r = (r==0) ? 0 : off[r-1], since consumed off[r-1]=orig off[r])
__global__ __launch_bounds__(256) void scatter_kernel(
    const int* __restrict__ idx, int* __restrict__ off,
    int* __restrict__ csr, int E)
{
    int e = blockIdx.x * 256 + threadIdx.x;
    if (e >= E) return;
    int s = idx[e];
    int r = idx[E + e];
    int pos = atomicAdd(&off[r], 1);
    csr[pos] = s;
}

// ---------------------------------------------------------------------------
// aggregate: one wave per node r; lane handles one PERMUTED feature pair.
// out[r] += sum_{s in in(r)} sigmoid(A[r]+B[s]) * S[s].  No atomics.
// R5: 4-edge unroll (8 independent row-gathers in flight) for gather MLP;
// final RMW uses the inverse permutation f_lo=(lane>>1)+64*(lane&1), +32.
// ---------------------------------------------------------------------------
__global__ __launch_bounds__(256) void aggregate_kernel(
    const int* __restrict__ off,          // consumed: off[r] = segment end
    const int* __restrict__ csr,
    const unsigned* __restrict__ A,       // bf16x2 per uint, [N][64] permuted
    const unsigned* __restrict__ B,
    const unsigned* __restrict__ S,
    float* __restrict__ out,
    int N)
{
    int r = blockIdx.x * 4 + (threadIdx.x >> 6);
    if (r >= N) return;
    int lane = threadIdx.x & 63;

    int start = (r == 0) ? 0 : off[r - 1];
    int end   = off[r];
    if (start >= end) return;             // deg 0: out already holds R

    unsigned ua = A[(size_t)r * 64 + lane];
    float a0 = bflo(ua), a1 = bfhi(ua);
    float acc0 = 0.0f, acc1 = 0.0f;

    int i = start;
    for (; i + 3 < end; i += 4) {
        int s0 = csr[i], s1 = csr[i + 1], s2 = csr[i + 2], s3 = csr[i + 3];
        unsigned ub0 = B[(size_t)s0 * 64 + lane];
        unsigned us0 = S[(size_t)s0 * 64 + lane];
        unsigned ub1 = B[(size_t)s1 * 64 + lane];
        unsigned us1 = S[(size_t)s1 * 64 + lane];
        unsigned ub2 = B[(size_t)s2 * 64 + lane];
        unsigned us2 = S[(size_t)s2 * 64 + lane];
        unsigned ub3 = B[(size_t)s3 * 64 + lane];
        unsigned us3 = S[(size_t)s3 * 64 + lane];
        acc0 += bflo(us0) * __builtin_amdgcn_rcpf(1.0f + __expf(-(a0 + bflo(ub0))));
        acc1 += bfhi(us0) * __builtin_amdgcn_rcpf(1.0f + __expf(-(a1 + bfhi(ub0))));
        acc0 += bflo(us1) * __builtin_amdgcn_rcpf(1.0f + __expf(-(a0 + bflo(ub1))));
        acc1 += bfhi(us1) * __builtin_amdgcn_rcpf(1.0f + __expf(-(a1 + bfhi(ub1))));
        acc0 += bflo(us2) * __builtin_amdgcn_rcpf(1.0f + __expf(-(a0 + bflo(ub2))));
        acc1 += bfhi(us2) * __builtin_amdgcn_rcpf(1.0f + __expf(-(a1 + bfhi(ub2))));
        acc0 += bflo(us3) * __builtin_amdgcn_rcpf(1.0f + __expf(-(a0 + bflo(ub3))));
        acc1 += bfhi(us3) * __builtin_amdgcn_rcpf(1.0f + __expf(-(a1 + bfhi(ub3))));
    }
    for (; i < end; ++i) {
        int s0 = csr[i];
        unsigned ub0 = B[(size_t)s0 * 64 + lane];
        unsigned us0 = S[(size_t)s0 * 64 + lane];
        acc0 += bflo(us0) * __builtin_amdgcn_rcpf(1.0f + __expf(-(a0 + bflo(ub0))));
        acc1 += bfhi(us0) * __builtin_amdgcn_rcpf(1.0f + __expf(-(a1 + bfhi(ub0))));
    }

    // inverse permutation: lane's uint held features (f0, f0+32)
    int f0 = (lane >> 1) + 64 * (lane & 1);
    float* o = out + (size_t)r * FD;
    o[f0]      += acc0;
    o[f0 + 32] += acc1;
}

// ---------------------------------------------------------------------------
extern "C" void kernel_launch(void* const* d_in, const int* in_sizes, int n_in,
                              void* d_out, int out_size, void* d_ws, size_t ws_size,
                              hipStream_t stream)
{
    const float* h  = (const float*)d_in[0];
    const int*   ei = (const int*)d_in[1];      // int32 per harness contract
    const float* Wg = (const float*)d_in[2];
    const float* bg = (const float*)d_in[3];
    const float* Ws = (const float*)d_in[4];
    const float* bs = (const float*)d_in[5];
    const float* Wr = (const float*)d_in[6];
    const float* br = (const float*)d_in[7];
    float* out = (float*)d_out;

    const int N = in_sizes[0] / FD;       // 100000
    const int E = in_sizes[1] / 2;        // 600000

    // Workspace layout:
    //   Wf [512*128 bf16] | A,B,S [N*128 bf16 each] | deg/off [N int] |
    //   partial [256 int] | csr [E int]
    unsigned short* Wf  = (unsigned short*)d_ws;
    unsigned short* Abf = Wf + 512 * FD;
    unsigned short* Bbf = Abf + (size_t)N * FD;
    unsigned short* Sbf = Bbf + (size_t)N * FD;
    int* deg     = (int*)(Sbf + (size_t)N * FD);   // becomes off after scan
    int* partial = deg + N;
    int* csr     = partial + 256;

    size_t need = (size_t)(512 * FD + 3ull * N * FD) * 2 + ((size_t)N + 256 + E) * 4;
    if (ws_size < need) return;   // diagnostic: absmax will equal memset-0 baseline

    const int nb = (N + 1023) / 1024;     // 98 scan blocks (<= 256 required)
    if (nb > 256) return;

    hipMemsetAsync(deg, 0, (size_t)N * 4, stream);

    prep_kernel<<<(512 * FD + 255) / 256, 256, 0, stream>>>(Wg, Ws, Wr, Wf);
    dim3 ggrid(256, 4);                   // 1024 blocks = 4 blocks/CU
    gemm_kernel<<<ggrid, 256, 0, stream>>>(h, Wf, bg, bs, br,
                                           Abf, Bbf, Sbf, out, N);
    hist_kernel<<<(E + 255) / 256, 256, 0, stream>>>(ei, deg, E);
    scan1_kernel<<<nb, 256, 0, stream>>>(deg, partial, N);
    scan2_kernel<<<1, 256, 0, stream>>>(partial, nb);
    scan3_kernel<<<nb, 256, 0, stream>>>(deg, partial, N);
    scatter_kernel<<<(E + 255) / 256, 256, 0, stream>>>(ei, deg, csr, E);
    aggregate_kernel<<<(N + 3) / 4, 256, 0, stream>>>(deg, csr,
                                                      (const unsigned*)Abf,
                                                      (const unsigned*)Bbf,
                                                      (const unsigned*)Sbf,
                                                      out, N);
}

// Round 6
// 283.257 us; speedup vs baseline: 1.3490x; 1.3490x over previous
//
#include <hip/hip_runtime.h>
#include <stdint.h>

// D = 128 fixed by the problem.
#define FD 128

typedef __bf16 bf16x8 __attribute__((ext_vector_type(8)));
typedef unsigned short u16x8 __attribute__((ext_vector_type(8)));
typedef float  f32x16 __attribute__((ext_vector_type(16)));

__device__ __forceinline__ unsigned short f2bf(float f) {
    unsigned u = __float_as_uint(f);
    unsigned r = u + 0x7fffu + ((u >> 16) & 1u);   // RNE
    return (unsigned short)(r >> 16);
}
__device__ __forceinline__ float bflo(unsigned u) { return __uint_as_float(u << 16); }
__device__ __forceinline__ float bfhi(unsigned u) { return __uint_as_float(u & 0xffff0000u); }

// ---------------------------------------------------------------------------
// Layouts (R6):
//   A  [N][128] bf16, canonical feature order (gate-rec term + bg).
//   BS [N][256] bf16: per node, B row (gate-send) at [0,128) then S row
//   (message content + bs) at [128,256). Interleaving B and S makes the
//   aggregate's per-edge gather one 512-B locality region instead of two
//   random touches in two 25.6-MB tables. Same total footprint as R4.
// gemm store pattern per instruction is IDENTICAL to R4 (2-B scalar,
// canonical cols) -- R5 showed changing the store shape destroys L2 reuse
// of h/Wf re-reads (FETCH 38 -> 254 MB). Only base/stride per w differ.
// ---------------------------------------------------------------------------

// ---------------------------------------------------------------------------
// prep: weights -> Wf, bf16 in MFMA B-fragment order:
//   Wf[((ct*8 + kt)*64 + lane)*8 + j] = W'[k = kt*16 + (lane>>5)*8 + j]
//                                         [c = ct*32 + (lane&31)]
// where W' = [Wg1 | Wg2 | Ws | Wr] (128 x 512). 512*128 elements = 128 KB.
// Quarter w (ct = 4w..4w+3) is contiguous: Wf[w*16384 .. (w+1)*16384).
// ---------------------------------------------------------------------------
__global__ __launch_bounds__(256) void prep_kernel(
    const float* __restrict__ Wg,
    const float* __restrict__ Ws,
    const float* __restrict__ Wr,
    unsigned short* __restrict__ Wf)
{
    int wid = blockIdx.x * 256 + threadIdx.x;      // 0 .. 65535
    if (wid >= 512 * 128) return;
    int j  = wid & 7;
    int l  = (wid >> 3) & 63;
    int kt = (wid >> 9) & 7;
    int ct = wid >> 12;                        // 0..15
    int k  = kt * 16 + (l >> 5) * 8 + j;       // 0..127
    int c  = ct * 32 + (l & 31);               // 0..511
    float v;
    if (c < 128)      v = Wg[k * FD + c];                    // Wg1
    else if (c < 256) v = Wg[(128 + k) * FD + (c - 128)];    // Wg2
    else if (c < 384) v = Ws[k * FD + (c - 256)];            // Ws
    else              v = Wr[k * FD + (c - 384)];            // Wr
    Wf[wid] = f2bf(v);
}

// ---------------------------------------------------------------------------
// gemm: [A|B|S|R] = h @ [Wg1|Wg2|Ws|Wr]  (N x 512 output, K = 128)
// R4 structure verbatim: LDS-stationary weights (stage once, one barrier,
// grid-stride, no hot-loop barriers), grid (256,4) = 4 blocks/CU.
// Epilogue: R4's canonical 2-B scalar stores; only dst base/row-stride
// differ per w (A vs interleaved BS vs fp32 out).
// ---------------------------------------------------------------------------
__global__ __launch_bounds__(256, 4) void gemm_kernel(
    const float* __restrict__ h,
    const unsigned short* __restrict__ Wf,
    const float* __restrict__ bg,
    const float* __restrict__ bs,
    const float* __restrict__ br,
    unsigned short* __restrict__ A,
    unsigned short* __restrict__ BS,
    float* __restrict__ out,
    int N)
{
    __shared__ unsigned short Bsh[16384];       // 32 KB: one weight quarter

    const int w    = blockIdx.y;                // 0..3: which weight matrix
    const int lane = threadIdx.x & 63;
    const int wid  = threadIdx.x >> 6;          // wave 0..3

    // ---- stage quarter w into LDS once: 8 passes x (256 threads x 16 B) ----
    {
        const unsigned short* src = Wf + (size_t)w * 16384 + (size_t)threadIdx.x * 8;
        unsigned short* dst = Bsh + (size_t)threadIdx.x * 8;
        #pragma unroll
        for (int p = 0; p < 8; ++p) {
            __builtin_amdgcn_global_load_lds(
                (const __attribute__((address_space(1))) void*)(src + p * 2048),
                (__attribute__((address_space(3))) void*)(dst + p * 2048),
                16, 0, 0);
        }
    }

    // per-wave constants
    const int col_l  = lane & 31;
    const int rhalf  = (lane >> 5) * 4;
    float bias[4];
    #pragma unroll
    for (int i = 0; i < 4; ++i) {
        int col = i * 32 + col_l;
        bias[i] = (w == 0) ? bg[col] : (w == 2) ? bs[col] : (w == 3) ? br[col] : 0.0f;
    }
    // bf16 destination (w = 0,1,2): base + row*rstride + col
    unsigned short* dst0 = (w == 0) ? A : (w == 2) ? (BS + 128) : BS;
    const size_t rstride = (w == 0) ? 128 : 256;

    __syncthreads();   // stage complete; no further barriers

    const int stride = gridDim.x * 128;         // rows per grid sweep (256*128)
    for (int rb0 = blockIdx.x * 128; rb0 < N; rb0 += stride) {
        const int rb = rb0 + wid * 32;
        int arow = rb + (lane & 31);
        if (arow >= N) arow = N - 1;      // clamp tail loads (dup work, guarded store)
        const float* aptr = h + (size_t)arow * FD + (lane >> 5) * 8;

        // A strip: 16 dwordx4, convert to 8 bf16x8 fragments
        bf16x8 afrag[8];
        #pragma unroll
        for (int kt = 0; kt < 8; ++kt) {
            float4 f0 = *(const float4*)(aptr + kt * 16);
            float4 f1 = *(const float4*)(aptr + kt * 16 + 4);
            union { u16x8 u; bf16x8 b; } cv;
            cv.u[0] = f2bf(f0.x); cv.u[1] = f2bf(f0.y);
            cv.u[2] = f2bf(f0.z); cv.u[3] = f2bf(f0.w);
            cv.u[4] = f2bf(f1.x); cv.u[5] = f2bf(f1.y);
            cv.u[6] = f2bf(f1.z); cv.u[7] = f2bf(f1.w);
            afrag[kt] = cv.b;
        }

        f32x16 acc[4];
        #pragma unroll
        for (int i = 0; i < 4; ++i)
            #pragma unroll
            for (int r = 0; r < 16; ++r) acc[i][r] = 0.0f;

        #pragma unroll
        for (int kt = 0; kt < 8; ++kt) {
            #pragma unroll
            for (int i = 0; i < 4; ++i) {
                bf16x8 bfr = *(const bf16x8*)(Bsh + (size_t)((i * 8 + kt) * 64 + lane) * 8);
                acc[i] = __builtin_amdgcn_mfma_f32_32x32x16_bf16(
                             afrag[kt], bfr, acc[i], 0, 0, 0);
            }
        }

        // C/D layout: col = lane&31, row = (reg&3) + 8*(reg>>2) + 4*(lane>>5)
        const bool interior = (rb + 32 <= N);
        if (w == 3) {
            // fp32 out, canonical cols.
            #pragma unroll
            for (int i = 0; i < 4; ++i) {
                int col = i * 32 + col_l;
                #pragma unroll
                for (int r = 0; r < 16; ++r) {
                    int row = rb + (r & 3) + 8 * (r >> 2) + rhalf;
                    if (interior || row < N)
                        out[(size_t)row * FD + col] = acc[i][r] + bias[i];
                }
            }
        } else {
            // bf16, canonical cols, R4 store shape.
            #pragma unroll
            for (int i = 0; i < 4; ++i) {
                int col = i * 32 + col_l;
                #pragma unroll
                for (int r = 0; r < 16; ++r) {
                    int row = rb + (r & 3) + 8 * (r >> 2) + rhalf;
                    if (interior || row < N)
                        dst0[(size_t)row * rstride + col] = f2bf(acc[i][r] + bias[i]);
                }
            }
        }
    }
}

// ---------------------------------------------------------------------------
// CSR build: histogram of receivers -> exclusive scan -> scatter send ids.
// idx is int32 [2][E] (harness converts int64 -> int32).
// ---------------------------------------------------------------------------
__global__ __launch_bounds__(256) void hist_kernel(
    const int* __restrict__ idx, int* __restrict__ deg, int E)
{
    int e = blockIdx.x * 256 + threadIdx.x;
    if (e >= E) return;
    atomicAdd(&deg[idx[E + e]], 1);
}

// scan pass 1: per-block sums of deg (1024 elems / block of 256 threads)
__global__ __launch_bounds__(256) void scan1_kernel(
    const int* __restrict__ deg, int* __restrict__ partial, int N)
{
    __shared__ int sh[256];
    int base = blockIdx.x * 1024 + threadIdx.x * 4;
    int s = 0;
    #pragma unroll
    for (int j = 0; j < 4; ++j) s += (base + j < N) ? deg[base + j] : 0;
    sh[threadIdx.x] = s;
    __syncthreads();
    for (int ofs = 128; ofs > 0; ofs >>= 1) {
        if (threadIdx.x < ofs) sh[threadIdx.x] += sh[threadIdx.x + ofs];
        __syncthreads();
    }
    if (threadIdx.x == 0) partial[blockIdx.x] = sh[0];
}

// scan pass 2: single block, exclusive scan of <=256 partials in place
__global__ __launch_bounds__(256) void scan2_kernel(int* __restrict__ partial, int nb)
{
    __shared__ int sh[256];
    int t = threadIdx.x;
    int p = (t < nb) ? partial[t] : 0;
    sh[t] = p;
    __syncthreads();
    for (int ofs = 1; ofs < 256; ofs <<= 1) {
        int x = (t >= ofs) ? sh[t - ofs] : 0;
        __syncthreads();
        sh[t] += x;
        __syncthreads();
    }
    if (t < nb) partial[t] = sh[t] - p;   // exclusive
}

// scan pass 3: recompute local exclusive scan + block offset; IN-PLACE deg->off
__global__ __launch_bounds__(256) void scan3_kernel(
    int* __restrict__ deg, const int* __restrict__ partial, int N)
{
    __shared__ int sh[256];
    int base = blockIdx.x * 1024 + threadIdx.x * 4;
    int v[4];
    #pragma unroll
    for (int j = 0; j < 4; ++j) v[j] = (base + j < N) ? deg[base + j] : 0;
    int tsum = v[0] + v[1] + v[2] + v[3];
    sh[threadIdx.x] = tsum;
    __syncthreads();
    for (int ofs = 1; ofs < 256; ofs <<= 1) {
        int x = (threadIdx.x >= ofs) ? sh[threadIdx.x - ofs] : 0;
        __syncthreads();
        sh[threadIdx.x] += x;
        __syncthreads();
    }
    int run = partial[blockIdx.x] + sh[threadIdx.x] - tsum;  // exclusive at base
    #pragma unroll
    for (int j = 0; j < 4; ++j) {
        if (base + j < N) deg[base + j] = run;
        run += v[j];
    }
}

// scatter: csr[pos] = send, consuming off (after: off[r] = end of segment r;
// start of segment r = (r==0) ? 0 : off[r-1], since consumed off[r-1]=orig off[r])
__global__ __launch_bounds__(256) void scatter_kernel(
    const int* __restrict__ idx, int* __restrict__ off,
    int* __restrict__ csr, int E)
{
    int e = blockIdx.x * 256 + threadIdx.x;
    if (e >= E) return;
    int s = idx[e];
    int r = idx[E + e];
    int pos = atomicAdd(&off[r], 1);
    csr[pos] = s;
}

// ---------------------------------------------------------------------------
// aggregate: one wave per node r; lane handles feature pair (2l, 2l+1).
// out[r] += sum_{s in in(r)} sigmoid(A[r]+B[s]) * S[s].  No atomics.
// R6: B,S interleaved per node (one 512-B locality region per edge gather);
// 4-edge unroll = 8 independent gathers in flight. Canonical float2 RMW.
// BS as uints: row = 128 uints; B pair at [s*128+lane], S at [s*128+64+lane].
// ---------------------------------------------------------------------------
__global__ __launch_bounds__(256) void aggregate_kernel(
    const int* __restrict__ off,          // consumed: off[r] = segment end
    const int* __restrict__ csr,
    const unsigned* __restrict__ A,       // bf16x2 per uint, [N][64]
    const unsigned* __restrict__ BS,      // bf16x2 per uint, [N][128] (B|S)
    float* __restrict__ out,
    int N)
{
    int r = blockIdx.x * 4 + (threadIdx.x >> 6);
    if (r >= N) return;
    int lane = threadIdx.x & 63;

    int start = (r == 0) ? 0 : off[r - 1];
    int end   = off[r];
    if (start >= end) return;             // deg 0: out already holds R

    unsigned ua = A[(size_t)r * 64 + lane];
    float a0 = bflo(ua), a1 = bfhi(ua);
    float acc0 = 0.0f, acc1 = 0.0f;

    int i = start;
    for (; i + 3 < end; i += 4) {
        int s0 = csr[i], s1 = csr[i + 1], s2 = csr[i + 2], s3 = csr[i + 3];
        unsigned ub0 = BS[(size_t)s0 * 128 + lane];
        unsigned us0 = BS[(size_t)s0 * 128 + 64 + lane];
        unsigned ub1 = BS[(size_t)s1 * 128 + lane];
        unsigned us1 = BS[(size_t)s1 * 128 + 64 + lane];
        unsigned ub2 = BS[(size_t)s2 * 128 + lane];
        unsigned us2 = BS[(size_t)s2 * 128 + 64 + lane];
        unsigned ub3 = BS[(size_t)s3 * 128 + lane];
        unsigned us3 = BS[(size_t)s3 * 128 + 64 + lane];
        acc0 += bflo(us0) * __builtin_amdgcn_rcpf(1.0f + __expf(-(a0 + bflo(ub0))));
        acc1 += bfhi(us0) * __builtin_amdgcn_rcpf(1.0f + __expf(-(a1 + bfhi(ub0))));
        acc0 += bflo(us1) * __builtin_amdgcn_rcpf(1.0f + __expf(-(a0 + bflo(ub1))));
        acc1 += bfhi(us1) * __builtin_amdgcn_rcpf(1.0f + __expf(-(a1 + bfhi(ub1))));
        acc0 += bflo(us2) * __builtin_amdgcn_rcpf(1.0f + __expf(-(a0 + bflo(ub2))));
        acc1 += bfhi(us2) * __builtin_amdgcn_rcpf(1.0f + __expf(-(a1 + bfhi(ub2))));
        acc0 += bflo(us3) * __builtin_amdgcn_rcpf(1.0f + __expf(-(a0 + bflo(ub3))));
        acc1 += bfhi(us3) * __builtin_amdgcn_rcpf(1.0f + __expf(-(a1 + bfhi(ub3))));
    }
    for (; i < end; ++i) {
        int s0 = csr[i];
        unsigned ub0 = BS[(size_t)s0 * 128 + lane];
        unsigned us0 = BS[(size_t)s0 * 128 + 64 + lane];
        acc0 += bflo(us0) * __builtin_amdgcn_rcpf(1.0f + __expf(-(a0 + bflo(ub0))));
        acc1 += bfhi(us0) * __builtin_amdgcn_rcpf(1.0f + __expf(-(a1 + bfhi(ub0))));
    }

    float2* o = (float2*)(out + (size_t)r * FD + 2 * lane);
    float2 cur = *o;
    cur.x += acc0;
    cur.y += acc1;
    *o = cur;
}

// ---------------------------------------------------------------------------
extern "C" void kernel_launch(void* const* d_in, const int* in_sizes, int n_in,
                              void* d_out, int out_size, void* d_ws, size_t ws_size,
                              hipStream_t stream)
{
    const float* h  = (const float*)d_in[0];
    const int*   ei = (const int*)d_in[1];      // int32 per harness contract
    const float* Wg = (const float*)d_in[2];
    const float* bg = (const float*)d_in[3];
    const float* Ws = (const float*)d_in[4];
    const float* bs = (const float*)d_in[5];
    const float* Wr = (const float*)d_in[6];
    const float* br = (const float*)d_in[7];
    float* out = (float*)d_out;

    const int N = in_sizes[0] / FD;       // 100000
    const int E = in_sizes[1] / 2;        // 600000

    // Workspace layout:
    //   Wf [512*128 bf16] | A [N*128 bf16] | BS [N*256 bf16] | deg/off [N int]
    //   | partial [256 int] | csr [E int]   (same total size as before)
    unsigned short* Wf  = (unsigned short*)d_ws;
    unsigned short* Abf = Wf + 512 * FD;
    unsigned short* BSb = Abf + (size_t)N * FD;
    int* deg     = (int*)(BSb + (size_t)N * 2 * FD);   // becomes off after scan
    int* partial = deg + N;
    int* csr     = partial + 256;

    size_t need = (size_t)(512 * FD + 3ull * N * FD) * 2 + ((size_t)N + 256 + E) * 4;
    if (ws_size < need) return;   // diagnostic: absmax will equal memset-0 baseline

    const int nb = (N + 1023) / 1024;     // 98 scan blocks (<= 256 required)
    if (nb > 256) return;

    hipMemsetAsync(deg, 0, (size_t)N * 4, stream);

    prep_kernel<<<(512 * FD + 255) / 256, 256, 0, stream>>>(Wg, Ws, Wr, Wf);
    dim3 ggrid(256, 4);                   // 1024 blocks = 4 blocks/CU
    gemm_kernel<<<ggrid, 256, 0, stream>>>(h, Wf, bg, bs, br,
                                           Abf, BSb, out, N);
    hist_kernel<<<(E + 255) / 256, 256, 0, stream>>>(ei, deg, E);
    scan1_kernel<<<nb, 256, 0, stream>>>(deg, partial, N);
    scan2_kernel<<<1, 256, 0, stream>>>(partial, nb);
    scan3_kernel<<<nb, 256, 0, stream>>>(deg, partial, N);
    scatter_kernel<<<(E + 255) / 256, 256, 0, stream>>>(ei, deg, csr, E);
    aggregate_kernel<<<(N + 3) / 4, 256, 0, stream>>>(deg, csr,
                                                      (const unsigned*)Abf,
                                                      (const unsigned*)BSb,
                                                      out, N);
}